// Round 7
// baseline (135.781 us; speedup 1.0000x reference)
//
#include <hip/hip_runtime.h>
#include <math.h>

#define N_NODES 50000
#define N_EDGES 800000
#define HIDDEN  64
#define NPART   500                   // partition blocks
#define PCHUNK  1600                  // edges per partition block (500*1600 = 800000)
#define NB      256                   // buckets == one block per bucket in agg kernels
#define SL      196                   // nodes per bucket; 256*196 = 50176 >= 50000
#define CAPB    32                    // per-(block,bucket) stage cap: mean 6.25, P(>=33)~4e-14
#define BCAP    3600                  // per-bucket capacity: mean 3125 + 8.5 sigma

// R6 post-mortem: 5 dispatches -> 27.7us ours (wall 108.2 = 80.5 fixed fills + ours).
// Per-dispatch fixed cost ~1.1us. R7: eliminate k_dg by computing deg via fire-and-forget
// global atomics in k_part (kernel boundary = free fence), consumers compute
// g[r] = rsqrt(deg[r]+1)*x[r] inline at gather time. 4 dispatches, no dinv/g arrays.

// ---- K1: radix partition into 256 dense buckets + degree atomics ----
__global__ __launch_bounds__(256)
void k_part(const int* __restrict__ row, const int* __restrict__ col,
            unsigned* __restrict__ tails, unsigned* __restrict__ bks,
            unsigned* __restrict__ deg) {
    __shared__ unsigned stage[NB * CAPB];           // 32 KB
    __shared__ unsigned cnt[NB], gpos[NB];
    const int t  = threadIdx.x;
    const int e0 = blockIdx.x * PCHUNK;
    cnt[t] = 0u;                                    // 256 threads == NB counters
    __syncthreads();
    const int4* c4 = (const int4*)(col + e0);
    const int4* r4 = (const int4*)(row + e0);
    for (int i = t; i < PCHUNK / 4; i += 256) {     // 400 int4s
        int4 cv = c4[i];
        int4 rv = r4[i];
#pragma unroll
        for (int k = 0; k < 4; ++k) {
            int c = (&cv.x)[k], r = (&rv.x)[k];
            atomicAdd(&deg[c], 1u);                 // fire-and-forget, pipelined
            int b = c / SL;                         // magic-mul div
            unsigned off = atomicAdd(&cnt[b], 1u);
            if (off < CAPB)
                stage[(b << 5) + off] = ((unsigned)(c - b * SL) << 16) | (unsigned)r;
        }
    }
    __syncthreads();
    {
        unsigned cc = min(cnt[t], (unsigned)CAPB);
        cnt[t]  = cc;
        gpos[t] = atomicAdd(&tails[t], cc);         // 128K global atomics, 256 addresses
    }
    __syncthreads();
    // dense flush: contiguous per-bucket segments
    for (int i = t; i < NB * CAPB; i += 256) {
        int b = i >> 5; unsigned o = (unsigned)(i & 31);
        if (o < cnt[b]) {
            unsigned dst = gpos[b] + o;
            if (dst < BCAP) bks[(size_t)b * BCAP + dst] = stage[i];
        }
    }
}

// ---- K2: layer-1 aggregation (inline g = rsqrt(deg+1)*x) + fused MLP -> z ----
__global__ __launch_bounds__(256)
void k_a1(const unsigned* __restrict__ tails, const unsigned* __restrict__ bks,
          const unsigned* __restrict__ deg, const float* __restrict__ x,
          const float* __restrict__ W1, const float* __restrict__ b1,
          const float* __restrict__ W2, float2* __restrict__ z) {
    __shared__ float acc[SL];
    const int t = threadIdx.x, b = blockIdx.x;
    if (t < SL) acc[t] = 0.0f;
    __syncthreads();
    unsigned tail = min(tails[b], (unsigned)BCAP);
    const unsigned* bk = bks + (size_t)b * BCAP;
    const uint4* bk4 = (const uint4*)bk;
    unsigned hv = tail & ~3u;
    for (unsigned i = t; (i << 2) < hv; i += 256) {
        uint4 v = bk4[i];
        unsigned r0 = v.x & 0xFFFFu, r1 = v.y & 0xFFFFu,
                 r2 = v.z & 0xFFFFu, r3 = v.w & 0xFFFFu;
        unsigned d0 = deg[r0], d1 = deg[r1], d2 = deg[r2], d3 = deg[r3];
        float x0 = x[r0], x1 = x[r1], x2 = x[r2], x3 = x[r3];
        float m0 = rsqrtf((float)(d0 + 1u)) * x0;
        float m1 = rsqrtf((float)(d1 + 1u)) * x1;
        float m2 = rsqrtf((float)(d2 + 1u)) * x2;
        float m3 = rsqrtf((float)(d3 + 1u)) * x3;
        atomicAdd(&acc[v.x >> 16], m0);
        atomicAdd(&acc[v.y >> 16], m1);
        atomicAdd(&acc[v.z >> 16], m2);
        atomicAdd(&acc[v.w >> 16], m3);
    }
    for (unsigned i = hv + t; i < tail; i += 256) {
        unsigned v = bk[i];
        unsigned r = v & 0xFFFFu;
        float m = rsqrtf((float)(deg[r] + 1u)) * x[r];
        atomicAdd(&acc[v >> 16], m);
    }
    __syncthreads();
    if (t < SL) {
        int n = b * SL + t;
        if (n < N_NODES) {
            float di = rsqrtf((float)(deg[n] + 1u));    // +1 self-loop
            float sv = di * (acc[t] + di * x[n]);       // + self-loop message
            float y0 = 0.0f, y1 = 0.0f;
#pragma unroll
            for (int k = 0; k < HIDDEN; ++k) {          // wave-uniform -> s_load
                float h = fmaxf(sv * W1[k] + b1[k], 0.0f);
                y0 += h * W2[2 * k];
                y1 += h * W2[2 * k + 1];
            }
            z[n] = make_float2(di * y0, di * y1);
        }
    }
}

// ---- K3: layer-2 aggregation (float2) + epilogue -> out ----
__global__ __launch_bounds__(256)
void k_a2(const unsigned* __restrict__ tails, const unsigned* __restrict__ bks,
          const unsigned* __restrict__ deg, const float2* __restrict__ z,
          const float* __restrict__ b2, float2* __restrict__ out) {
    __shared__ float ax[SL];
    __shared__ float ay[SL];
    const int t = threadIdx.x, b = blockIdx.x;
    if (t < SL) { ax[t] = 0.0f; ay[t] = 0.0f; }
    __syncthreads();
    unsigned tail = min(tails[b], (unsigned)BCAP);
    const unsigned* bk = bks + (size_t)b * BCAP;
    const uint4* bk4 = (const uint4*)bk;
    unsigned hv = tail & ~3u;
    for (unsigned i = t; (i << 2) < hv; i += 256) {
        uint4 v = bk4[i];
        float2 z0 = z[v.x & 0xFFFFu];
        float2 z1 = z[v.y & 0xFFFFu];
        float2 z2 = z[v.z & 0xFFFFu];
        float2 z3 = z[v.w & 0xFFFFu];
        atomicAdd(&ax[v.x >> 16], z0.x); atomicAdd(&ay[v.x >> 16], z0.y);
        atomicAdd(&ax[v.y >> 16], z1.x); atomicAdd(&ay[v.y >> 16], z1.y);
        atomicAdd(&ax[v.z >> 16], z2.x); atomicAdd(&ay[v.z >> 16], z2.y);
        atomicAdd(&ax[v.w >> 16], z3.x); atomicAdd(&ay[v.w >> 16], z3.y);
    }
    for (unsigned i = hv + t; i < tail; i += 256) {
        unsigned v = bk[i];
        float2 zz = z[v & 0xFFFFu];
        atomicAdd(&ax[v >> 16], zz.x);
        atomicAdd(&ay[v >> 16], zz.y);
    }
    __syncthreads();
    if (t < SL) {
        int n = b * SL + t;
        if (n < N_NODES) {
            float di = rsqrtf((float)(deg[n] + 1u));
            float2 zn = z[n];
            out[n] = make_float2(di * (ax[t] + zn.x) + b2[0],
                                 di * (ay[t] + zn.y) + b2[1]);
        }
    }
}

// ================= launch =================

extern "C" void kernel_launch(void* const* d_in, const int* in_sizes, int n_in,
                              void* d_out, int out_size, void* d_ws, size_t ws_size,
                              hipStream_t stream) {
    const float* x  = (const float*)d_in[0];
    const int*   ei = (const int*)d_in[1];
    const float* W1 = (const float*)d_in[2];
    const float* b1 = (const float*)d_in[3];
    const float* W2 = (const float*)d_in[4];
    const float* b2 = (const float*)d_in[5];

    const int* row = ei;
    const int* col = ei + N_EDGES;

    char* p = (char*)d_ws;
    unsigned* deg   = (unsigned*)p;  p += 50176 * 4;                   // 200.7 KB
    unsigned* tails = (unsigned*)p;  p += 1024;                        // 256 u32
    unsigned* bks   = (unsigned*)p;  p += (size_t)NB * BCAP * 4;       // 3.7 MB
    float2*   z     = (float2*)p;

    // one memset covers deg + tails (contiguous)
    hipMemsetAsync(deg, 0, 50176 * 4 + 1024, stream);
    k_part<<<NPART, 256, 0, stream>>>(row, col, tails, bks, deg);
    k_a1  <<<NB,    256, 0, stream>>>(tails, bks, deg, x, W1, b1, W2, z);
    k_a2  <<<NB,    256, 0, stream>>>(tails, bks, deg, z, b2, (float2*)d_out);
}

// Round 8
// 107.577 us; speedup vs baseline: 1.2622x; 1.2622x over previous
//
#include <hip/hip_runtime.h>
#include <math.h>

#define N_NODES 50000
#define N_EDGES 800000
#define HIDDEN  64
#define NPART   500                   // partition blocks
#define PCHUNK  1600                  // edges per partition block (500*1600 = 800000)
#define NB      256                   // buckets == one block per bucket in agg kernels
#define SL      196                   // nodes per bucket; 256*196 = 50176 >= 50000
#define CAPB    32                    // per-(block,bucket) stage cap: mean 6.25, P(>=33)~4e-14
#define BCAP    3600                  // per-bucket capacity: mean 3125 + 8.5 sigma

// Session ledger (keep: hard-won structural facts for this problem/harness):
// - Wall = ~80.5us harness poison fills (2x 268MB fillBuffer in timed stream, untouchable)
//   + ~1.1us per dispatch + kernel bodies. R6's 5-dispatch structure = 108.2us verified best.
// - R2: cooperative grid.sync ~50us/sync at 512 WGs -> never grid-sync sub-100us pipelines.
// - R5: __threadfence producer->consumer handshake ~80us/kernel (per-XCD L2 writeback).
// - R7: scattered device-scope atomicAdd = memory-side 32B RMW, ~34ns each; 800K of them
//   cost +27us in k_part. Kernel boundary (~1.1us) is the cheapest device-wide fence.
// - R3: agg-interior tweaks (sub-block count, uint4 gather ILP) are null -> bodies are
//   gather-latency bound at ~6x BW floor; not the lever.

// ---- K1: write-combined radix partition into 256 dense buckets ----
__global__ __launch_bounds__(256)
void k_part(const int* __restrict__ row, const int* __restrict__ col,
            unsigned* __restrict__ tails, unsigned* __restrict__ bks) {
    __shared__ unsigned stage[NB * CAPB];           // 32 KB
    __shared__ unsigned cnt[NB], gpos[NB];
    const int t  = threadIdx.x;
    const int e0 = blockIdx.x * PCHUNK;
    cnt[t] = 0u;                                    // 256 threads == NB counters
    __syncthreads();
    const int4* c4 = (const int4*)(col + e0);
    const int4* r4 = (const int4*)(row + e0);
    for (int i = t; i < PCHUNK / 4; i += 256) {     // 400 int4s
        int4 cv = c4[i];
        int4 rv = r4[i];
#pragma unroll
        for (int k = 0; k < 4; ++k) {
            int c = (&cv.x)[k], r = (&rv.x)[k];
            int b = c / SL;                         // magic-mul div
            unsigned off = atomicAdd(&cnt[b], 1u);
            if (off < CAPB)
                stage[(b << 5) + off] = ((unsigned)(c - b * SL) << 16) | (unsigned)r;
        }
    }
    __syncthreads();
    {
        unsigned cc = min(cnt[t], (unsigned)CAPB);
        cnt[t]  = cc;
        gpos[t] = atomicAdd(&tails[t], cc);         // 128K global atomics, 256 addresses
    }
    __syncthreads();
    // dense flush: contiguous per-bucket segments
    for (int i = t; i < NB * CAPB; i += 256) {
        int b = i >> 5; unsigned o = (unsigned)(i & 31);
        if (o < cnt[b]) {
            unsigned dst = gpos[b] + o;
            if (dst < BCAP) bks[(size_t)b * BCAP + dst] = stage[i];
        }
    }
}

// ---- K2: per-bucket degree histogram -> dinv, g  (one block per bucket) ----
__global__ __launch_bounds__(256)
void k_dg(const unsigned* __restrict__ tails, const unsigned* __restrict__ bks,
          const float* __restrict__ x, float* __restrict__ dinv, float* __restrict__ g) {
    __shared__ unsigned acc[SL];                    // 784 B
    const int t = threadIdx.x, b = blockIdx.x;
    if (t < SL) acc[t] = 0u;
    __syncthreads();
    unsigned tail = min(tails[b], (unsigned)BCAP);
    const unsigned* bk = bks + (size_t)b * BCAP;
    const uint4* bk4 = (const uint4*)bk;
    unsigned hv = tail & ~3u;
    for (unsigned i = t; (i << 2) < hv; i += 256) {
        uint4 v = bk4[i];
        atomicAdd(&acc[v.x >> 16], 1u);
        atomicAdd(&acc[v.y >> 16], 1u);
        atomicAdd(&acc[v.z >> 16], 1u);
        atomicAdd(&acc[v.w >> 16], 1u);
    }
    for (unsigned i = hv + t; i < tail; i += 256)
        atomicAdd(&acc[bk[i] >> 16], 1u);
    __syncthreads();
    if (t < SL) {
        int n = b * SL + t;
        if (n < N_NODES) {
            float di = rsqrtf((float)(acc[t] + 1u));    // +1 self-loop
            dinv[n] = di;
            g[n] = di * x[n];
        }
    }
}

// ---- K3: layer-1 aggregation + fused MLP -> z  (one block per bucket) ----
__global__ __launch_bounds__(256)
void k_a1(const unsigned* __restrict__ tails, const unsigned* __restrict__ bks,
          const float* __restrict__ g, const float* __restrict__ dinv,
          const float* __restrict__ W1, const float* __restrict__ b1,
          const float* __restrict__ W2, float2* __restrict__ z) {
    __shared__ float acc[SL];
    const int t = threadIdx.x, b = blockIdx.x;
    if (t < SL) acc[t] = 0.0f;
    __syncthreads();
    unsigned tail = min(tails[b], (unsigned)BCAP);
    const unsigned* bk = bks + (size_t)b * BCAP;
    const uint4* bk4 = (const uint4*)bk;
    unsigned hv = tail & ~3u;
    for (unsigned i = t; (i << 2) < hv; i += 256) {
        uint4 v = bk4[i];
        float g0 = g[v.x & 0xFFFFu];
        float g1 = g[v.y & 0xFFFFu];
        float g2 = g[v.z & 0xFFFFu];
        float g3 = g[v.w & 0xFFFFu];
        atomicAdd(&acc[v.x >> 16], g0);
        atomicAdd(&acc[v.y >> 16], g1);
        atomicAdd(&acc[v.z >> 16], g2);
        atomicAdd(&acc[v.w >> 16], g3);
    }
    for (unsigned i = hv + t; i < tail; i += 256) {
        unsigned v = bk[i];
        atomicAdd(&acc[v >> 16], g[v & 0xFFFFu]);
    }
    __syncthreads();
    if (t < SL) {
        int n = b * SL + t;
        if (n < N_NODES) {
            float di = dinv[n];
            float sv = di * (acc[t] + g[n]);        // + self-loop message
            float y0 = 0.0f, y1 = 0.0f;
#pragma unroll
            for (int k = 0; k < HIDDEN; ++k) {      // wave-uniform -> s_load
                float h = fmaxf(sv * W1[k] + b1[k], 0.0f);
                y0 += h * W2[2 * k];
                y1 += h * W2[2 * k + 1];
            }
            z[n] = make_float2(di * y0, di * y1);
        }
    }
}

// ---- K4: layer-2 aggregation (float2) + epilogue -> out  (one block per bucket) ----
__global__ __launch_bounds__(256)
void k_a2(const unsigned* __restrict__ tails, const unsigned* __restrict__ bks,
          const float2* __restrict__ z, const float* __restrict__ dinv,
          const float* __restrict__ b2, float2* __restrict__ out) {
    __shared__ float ax[SL];
    __shared__ float ay[SL];
    const int t = threadIdx.x, b = blockIdx.x;
    if (t < SL) { ax[t] = 0.0f; ay[t] = 0.0f; }
    __syncthreads();
    unsigned tail = min(tails[b], (unsigned)BCAP);
    const unsigned* bk = bks + (size_t)b * BCAP;
    const uint4* bk4 = (const uint4*)bk;
    unsigned hv = tail & ~3u;
    for (unsigned i = t; (i << 2) < hv; i += 256) {
        uint4 v = bk4[i];
        float2 z0 = z[v.x & 0xFFFFu];
        float2 z1 = z[v.y & 0xFFFFu];
        float2 z2 = z[v.z & 0xFFFFu];
        float2 z3 = z[v.w & 0xFFFFu];
        atomicAdd(&ax[v.x >> 16], z0.x); atomicAdd(&ay[v.x >> 16], z0.y);
        atomicAdd(&ax[v.y >> 16], z1.x); atomicAdd(&ay[v.y >> 16], z1.y);
        atomicAdd(&ax[v.z >> 16], z2.x); atomicAdd(&ay[v.z >> 16], z2.y);
        atomicAdd(&ax[v.w >> 16], z3.x); atomicAdd(&ay[v.w >> 16], z3.y);
    }
    for (unsigned i = hv + t; i < tail; i += 256) {
        unsigned v = bk[i];
        float2 zz = z[v & 0xFFFFu];
        atomicAdd(&ax[v >> 16], zz.x);
        atomicAdd(&ay[v >> 16], zz.y);
    }
    __syncthreads();
    if (t < SL) {
        int n = b * SL + t;
        if (n < N_NODES) {
            float di = dinv[n];
            float2 zn = z[n];
            out[n] = make_float2(di * (ax[t] + zn.x) + b2[0],
                                 di * (ay[t] + zn.y) + b2[1]);
        }
    }
}

// ================= launch =================

extern "C" void kernel_launch(void* const* d_in, const int* in_sizes, int n_in,
                              void* d_out, int out_size, void* d_ws, size_t ws_size,
                              hipStream_t stream) {
    const float* x  = (const float*)d_in[0];
    const int*   ei = (const int*)d_in[1];
    const float* W1 = (const float*)d_in[2];
    const float* b1 = (const float*)d_in[3];
    const float* W2 = (const float*)d_in[4];
    const float* b2 = (const float*)d_in[5];

    const int* row = ei;
    const int* col = ei + N_EDGES;

    char* p = (char*)d_ws;
    unsigned* tails = (unsigned*)p;  p += 1024 + 128;                  // 256 u32 (+pad)
    unsigned* bks   = (unsigned*)p;  p += (size_t)NB * BCAP * 4;       // 3.7 MB
    float*    dinv  = (float*)p;     p += 200064;
    float*    g     = (float*)p;     p += 200064;
    float2*   z     = (float2*)p;

    hipMemsetAsync(tails, 0, NB * sizeof(unsigned), stream);
    k_part<<<NPART, 256, 0, stream>>>(row, col, tails, bks);
    k_dg  <<<NB,    256, 0, stream>>>(tails, bks, x, dinv, g);
    k_a1  <<<NB,    256, 0, stream>>>(tails, bks, g, dinv, W1, b1, W2, z);
    k_a2  <<<NB,    256, 0, stream>>>(tails, bks, z, dinv, b2, (float2*)d_out);
}